// Round 10
// baseline (243.547 us; speedup 1.0000x reference)
//
#include <hip/hip_runtime.h>

#define T_NUM   100000
#define W_NUM   500
#define N_NODES 100500
#define A_NUM   1000000
#define FEAT    512
#define HID     128
#define CLS     10

#define CSR_STRIDE  40       // per-task worker slots; Poisson(10) tail @40 ~ 3e-16
#define CSRT_STRIDE 2432     // per-worker task slots; Binomial(1M,1/500) 9-sigma
#define BM          64       // GEMM rows per block (4 waves x 16 rows)
#define HPAD        136      // Hs row stride (bf16 elems)
#define NRANGE      8        // XCD count
#define TRNG        (T_NUM / NRANGE)   // 12500 tasks per XCD range
#define CHUNK       2048     // answers per work-stealing chunk
#define NCHUNK      ((A_NUM + CHUNK - 1) / CHUNK)   // 489

typedef short bf16x8 __attribute__((ext_vector_type(8)));
typedef float f32x4  __attribute__((ext_vector_type(4)));

__device__ __forceinline__ unsigned short f2bf(float f) {
    unsigned int u = __float_as_uint(f);
    unsigned int r = (u + 0x7FFFu + ((u >> 16) & 1u)) >> 16;  // RNE
    return (unsigned short)r;
}

// ---------------- K1: CSR build, pinned to the block's ACTUAL XCD ---------
// Each block reads its hardware XCD id (dispatch mapping is undefined, so we
// don't guess from blockIdx) and serves only that XCD's task range
// [r*12500,(r+1)*12500) and worker range (w>>6)==r. Per-XCD work-stealing
// tickets give exact, balanced coverage of all answers per XCD. Result: each
// XCD's csrW slice (~1MB) + csrT slice (~0.6MB) stay resident in its own L2,
// so scattered-store writebacks ~= payload instead of 64B-line thrash.
__global__ __launch_bounds__(256) void k_build(
        const int* __restrict__ answers, int* __restrict__ cnt,
        int* __restrict__ wcur, int* __restrict__ tick,
        unsigned short* __restrict__ csrW, int* __restrict__ csrT) {
    __shared__ int s_chunk;
    int xcc;
    asm volatile("s_getreg_b32 %0, hwreg(HW_REG_XCC_ID)" : "=s"(xcc));
    const int r   = xcc & (NRANGE - 1);
    const int tlo = r * TRNG, thi = tlo + TRNG;

    for (;;) {
        if (threadIdx.x == 0) s_chunk = atomicAdd(&tick[r * 16], 1);
        __syncthreads();
        const int c = s_chunk;
        if (c >= NCHUNK) break;
        const int base = c * CHUNK;
        const int end  = (base + CHUNK < A_NUM) ? base + CHUNK : A_NUM;
        for (int a = base + threadIdx.x; a < end; a += 256) {
            int t = answers[a * 3 + 0];
            int w = answers[a * 3 + 1];
            if (t >= tlo && t < thi) {
                int p = atomicAdd(&cnt[t], 1);
                if (p < CSR_STRIDE) csrW[(size_t)t * CSR_STRIDE + p] = (unsigned short)w;
            }
            if ((w >> 6) == r) {
                int q = atomicAdd(&wcur[w * 16], 1);       // 64B-padded cursors
                if (q < CSRT_STRIDE) csrT[(size_t)w * CSRT_STRIDE + q] = t;
            }
        }
        __syncthreads();   // all lanes consumed s_chunk before next ticket
    }
}

// ---------------- K2: weight preps + worker projections ----------------
__global__ void k_prepw(const float* __restrict__ W, unsigned short* __restrict__ Wt,
                        unsigned short* __restrict__ B2t,
                        const float* __restrict__ WF,
                        const float* __restrict__ Wm, const float* __restrict__ Wl,
                        const int* __restrict__ wcur,
                        float* __restrict__ g) {
    int bid = blockIdx.x;
    if (bid < HID) {
        int c = bid;
        for (int k = threadIdx.x; k < FEAT; k += blockDim.x)
            Wt[(size_t)c * FEAT + k] = f2bf(W[(size_t)k * HID + c]);
    } else if (bid == HID) {
        for (int i = threadIdx.x; i < 32 * HID; i += blockDim.x) {
            int c = i / HID, k = i % HID;
            float v = 0.f;
            if (c < 10)                 v = Wm[k * CLS + c];
            else if (c >= 16 && c < 26) v = Wl[k * CLS + (c - 16)];
            B2t[i] = f2bf(v);
        }
    } else {
        int idx = (bid - HID - 1) * blockDim.x + threadIdx.x;
        if (idx >= W_NUM * 20) return;
        int w = idx / 20, oc = idx % 20;
        const float* Wc = (oc < 10) ? (Wm + oc) : (Wl + (oc - 10));
        const float* x  = WF + (size_t)w * HID;
        float s = 0.f;
        #pragma unroll 8
        for (int k = 0; k < HID; k++) s = fmaf(x[k], Wc[k * CLS], s);
        float gi = rsqrtf((float)(wcur[w * 16] + 1)) * s;
        g[(size_t)(T_NUM + w) * 20 + oc] = gi;
    }
}

// ---------------- K3: MFMA GEMM (Hs overlaid on Bb; high occupancy) -------
__global__ __launch_bounds__(256, 7) void k_gemm_mfma(
        const float* __restrict__ A, const unsigned short* __restrict__ Wt,
        const float* __restrict__ bias, const unsigned short* __restrict__ B2t,
        const int* __restrict__ cnt, float* __restrict__ g) {
    __shared__ __align__(16) char smem[17408];

    const int tid  = threadIdx.x;
    const int lane = tid & 63;
    const int wv   = tid >> 6;                    // 0..3
    const int l15  = lane & 15;
    const int lkg  = lane >> 4;                   // 0..3
    const int row  = blockIdx.x * BM + wv * 16 + l15;
    const int rowc = row < T_NUM ? row : T_NUM - 1;   // clamp reads
    const float* aptr = A + (size_t)rowc * FEAT + lkg * 8;

    const int scol  = tid >> 1;                   // 0..127
    const int shalf = tid & 1;
    const int sswz  = (scol & 7) << 4;
    const int sb0   = (scol * 64 + shalf * 32) ^ sswz;
    const int sb1   = (scol * 64 + shalf * 32 + 16) ^ sswz;
    const unsigned short* sptr = Wt + (size_t)scol * FEAT + shalf * 16;

    const int rswz = (l15 & 7) << 4;

    f32x4 acc[8];
    #pragma unroll
    for (int nt = 0; nt < 8; nt++) acc[nt] = (f32x4){0.f, 0.f, 0.f, 0.f};

    union LU { int4 i; bf16x8 h; };
    union PK { unsigned short u[8]; bf16x8 h; };

    float4 ca0 = *(const float4*)(aptr);
    float4 ca1 = *(const float4*)(aptr + 4);
    *(int4*)(smem + sb0) = *(const int4*)(sptr);
    *(int4*)(smem + sb1) = *(const int4*)(sptr + 8);
    __syncthreads();

    for (int ks = 0; ks < 16; ks++) {
        const int k0 = ks * 32;
        float4 na0, na1;
        if (ks < 15) {
            na0 = *(const float4*)(aptr + k0 + 32);
            na1 = *(const float4*)(aptr + k0 + 36);
            char* nb = smem + (((ks + 1) & 1) << 13);
            *(int4*)(nb + sb0) = *(const int4*)(sptr + k0 + 32);
            *(int4*)(nb + sb1) = *(const int4*)(sptr + k0 + 40);
        }
        PK pk;
        pk.u[0] = f2bf(ca0.x); pk.u[1] = f2bf(ca0.y);
        pk.u[2] = f2bf(ca0.z); pk.u[3] = f2bf(ca0.w);
        pk.u[4] = f2bf(ca1.x); pk.u[5] = f2bf(ca1.y);
        pk.u[6] = f2bf(ca1.z); pk.u[7] = f2bf(ca1.w);
        const char* bb = smem + ((ks & 1) << 13);
        #pragma unroll
        for (int nt = 0; nt < 8; nt++) {
            const int boff = ((nt * 16 + l15) * 64 + lkg * 16) ^ rswz;
            LU bu; bu.i = *(const int4*)(bb + boff);
            acc[nt] = __builtin_amdgcn_mfma_f32_16x16x32_bf16(pk.h, bu.h, acc[nt], 0, 0, 0);
        }
        ca0 = na0; ca1 = na1;
        __syncthreads();
    }

    // ---- epilogue: H = relu(acc + bias) -> per-wave LDS region (bf16)
    unsigned short* hw = (unsigned short*)smem + wv * 16 * HPAD;
    #pragma unroll
    for (int nt = 0; nt < 8; nt++) {
        float bv = bias[nt * 16 + l15];
        #pragma unroll
        for (int r = 0; r < 4; r++) {
            float h = fmaxf(acc[nt][r] + bv, 0.f);
            hw[(lkg * 4 + r) * HPAD + nt * 16 + l15] = f2bf(h);
        }
    }

    // ---- second MFMA stage: g_pre = H(16x128) @ B2(128x32)
    f32x4 acc2[2];
    acc2[0] = (f32x4){0.f, 0.f, 0.f, 0.f};
    acc2[1] = (f32x4){0.f, 0.f, 0.f, 0.f};
    #pragma unroll
    for (int s = 0; s < 4; s++) {
        LU a2;
        a2.i = *(const int4*)(hw + l15 * HPAD + s * 32 + lkg * 8);
        #pragma unroll
        for (int j = 0; j < 2; j++) {
            LU b2;
            b2.i = *(const int4*)(B2t + (size_t)(j * 16 + l15) * HID + s * 32 + lkg * 8);
            acc2[j] = __builtin_amdgcn_mfma_f32_16x16x32_bf16(a2.h, b2.h, acc2[j], 0, 0, 0);
        }
    }

    // ---- scale by dinv and write g[node][0..19]
    if (l15 < 10) {
        #pragma unroll
        for (int r = 0; r < 4; r++) {
            int node = blockIdx.x * BM + wv * 16 + lkg * 4 + r;
            if (node < T_NUM) {
                float di = rsqrtf((float)(cnt[node] + 1));
                g[(size_t)node * 20 + l15]      = di * acc2[0][r];
                g[(size_t)node * 20 + 10 + l15] = di * acc2[1][r];
            }
        }
    }
}

// ---------------- K4: worker accumulation by gather + finalize ------------
__global__ __launch_bounds__(256) void k_wacc(
        const int* __restrict__ csrT, const int* __restrict__ wcur,
        const float* __restrict__ g,
        const float* __restrict__ b_mean, const float* __restrict__ b_ls,
        const float* __restrict__ eps,
        float* __restrict__ out_mean, float* __restrict__ out_ls,
        float* __restrict__ z) {
    const int w    = blockIdx.x;
    const int tid  = threadIdx.x;
    const int lane = tid & 63;
    const int wv   = tid >> 6;

    int len = wcur[w * 16];
    int lim = len < CSRT_STRIDE ? len : CSRT_STRIDE;
    const int* lst = csrT + (size_t)w * CSRT_STRIDE;

    float a[20];
    #pragma unroll
    for (int c = 0; c < 20; c++) a[c] = 0.f;

    for (int e = tid; e < lim; e += 256) {
        int t = lst[e];
        const float4* gr = (const float4*)(g + (size_t)t * 20);
        float4 v0 = gr[0], v1 = gr[1], v2 = gr[2], v3 = gr[3], v4 = gr[4];
        a[0] += v0.x; a[1] += v0.y; a[2] += v0.z; a[3] += v0.w;
        a[4] += v1.x; a[5] += v1.y; a[6] += v1.z; a[7] += v1.w;
        a[8] += v2.x; a[9] += v2.y; a[10] += v2.z; a[11] += v2.w;
        a[12] += v3.x; a[13] += v3.y; a[14] += v3.z; a[15] += v3.w;
        a[16] += v4.x; a[17] += v4.y; a[18] += v4.z; a[19] += v4.w;
    }

    #pragma unroll
    for (int off = 32; off; off >>= 1) {
        #pragma unroll
        for (int c = 0; c < 20; c++) a[c] += __shfl_down(a[c], off, 64);
    }

    __shared__ float wpart[4][20];
    __shared__ float fin[20];
    if (lane == 0) {
        #pragma unroll
        for (int c = 0; c < 20; c++) wpart[wv][c] = a[c];
    }
    __syncthreads();

    const int node = T_NUM + w;
    if (tid < 20) {
        float s = wpart[0][tid] + wpart[1][tid] + wpart[2][tid] + wpart[3][tid];
        float di = rsqrtf((float)(len + 1));
        float gv = g[(size_t)node * 20 + tid];
        if (tid < 10) {
            float m = fmaf(di, s + gv, b_mean[tid]);
            out_mean[(size_t)node * CLS + tid] = m;
            fin[tid] = m;
        } else {
            int c = tid - 10;
            float l = fmaf(di, s + gv, b_ls[c]);
            out_ls[(size_t)node * CLS + c] = l;
            fin[tid] = l;
        }
    }
    __syncthreads();
    if (tid < 10) {
        float m = fin[tid], l = fin[tid + 10];
        z[(size_t)node * CLS + tid] =
            fmaf(eps[(size_t)node * CLS + tid] * 0.01f, expf(l), m);
    }
}

// ---------------- K5: task-side gather + finalize ----------------
__global__ __launch_bounds__(256) void k_gather_task(
        const int* __restrict__ cnt, const unsigned short* __restrict__ csrW,
        const float* __restrict__ g,
        const float* __restrict__ b_mean, const float* __restrict__ b_ls,
        const float* __restrict__ eps,
        float* __restrict__ out_mean, float* __restrict__ out_ls,
        float* __restrict__ z) {
    __shared__ float gw[W_NUM * 21];
    for (int i = threadIdx.x; i < W_NUM * 20; i += blockDim.x)
        gw[(i / 20) * 21 + (i % 20)] = g[(size_t)T_NUM * 20 + i];
    __syncthreads();

    int t = blockIdx.x * blockDim.x + threadIdx.x;
    if (t >= T_NUM) return;

    int len = cnt[t];
    int lim = len < CSR_STRIDE ? len : CSR_STRIDE;
    const unsigned short* lst = csrW + (size_t)t * CSR_STRIDE;
    float am[10], al[10];
    #pragma unroll
    for (int c = 0; c < 10; c++) { am[c] = 0.f; al[c] = 0.f; }

    for (int e = 0; e < lim; e++) {
        const float* gg = &gw[lst[e] * 21];
        #pragma unroll
        for (int c = 0; c < 10; c++) {
            am[c] += gg[c];
            al[c] += gg[10 + c];
        }
    }

    float di = rsqrtf((float)(len + 1));
    union { float4 v[5]; float f[20]; } grow;
    const float4* gr = (const float4*)(g + (size_t)t * 20);
    #pragma unroll
    for (int c = 0; c < 5; c++) grow.v[c] = gr[c];

    const float2* ep2 = (const float2*)(eps + (size_t)t * CLS);
    float2* om2 = (float2*)(out_mean + (size_t)t * CLS);
    float2* ol2 = (float2*)(out_ls + (size_t)t * CLS);
    float2* z2  = (float2*)(z + (size_t)t * CLS);
    #pragma unroll
    for (int c = 0; c < 5; c++) {
        float2 ev = ep2[c];
        float m0 = fmaf(di, am[2 * c] + grow.f[2 * c], b_mean[2 * c]);
        float m1 = fmaf(di, am[2 * c + 1] + grow.f[2 * c + 1], b_mean[2 * c + 1]);
        float l0 = fmaf(di, al[2 * c] + grow.f[10 + 2 * c], b_ls[2 * c]);
        float l1 = fmaf(di, al[2 * c + 1] + grow.f[10 + 2 * c + 1], b_ls[2 * c + 1]);
        om2[c] = make_float2(m0, m1);
        ol2[c] = make_float2(l0, l1);
        z2[c]  = make_float2(fmaf(ev.x * 0.01f, expf(l0), m0),
                             fmaf(ev.y * 0.01f, expf(l1), m1));
    }
}

// ---------------- K6: crowd_out (thread per answer) ----------------
__global__ void k_crowd(const int* __restrict__ answers, const float* __restrict__ z,
                        float* __restrict__ out) {
    int a = blockIdx.x * blockDim.x + threadIdx.x;
    if (a >= A_NUM) return;
    int t = answers[a * 3 + 0];
    int w = answers[a * 3 + 1];
    const float2* zt = (const float2*)(z + (size_t)t * CLS);
    const float2* zw = (const float2*)(z + (size_t)(T_NUM + w) * CLS);
    float2* o = (float2*)(out + (size_t)a * CLS);
    #pragma unroll
    for (int c = 0; c < 5; c++) {
        float2 x = zt[c], y = zw[c];
        o[c] = make_float2(x.x * y.x, x.y * y.y);
    }
}

extern "C" void kernel_launch(void* const* d_in, const int* in_sizes, int n_in,
                              void* d_out, int out_size, void* d_ws, size_t ws_size,
                              hipStream_t stream) {
    const float* task_feature   = (const float*)d_in[0];
    const int*   answers        = (const int*)d_in[1];
    const float* worker_feature = (const float*)d_in[2];
    const float* W_efc          = (const float*)d_in[3];
    const float* b_efc          = (const float*)d_in[4];
    const float* W_mean         = (const float*)d_in[5];
    const float* b_mean         = (const float*)d_in[6];
    const float* W_ls           = (const float*)d_in[7];
    const float* b_ls           = (const float*)d_in[8];
    const float* eps            = (const float*)d_in[9];

    float* out       = (float*)d_out;
    float* out_crowd = out;                              // [A, C]
    float* out_mean  = out + (size_t)A_NUM * CLS;        // [N, C]
    float* out_ls    = out_mean + (size_t)N_NODES * CLS; // [N, C]

    // workspace layout
    char* ws = (char*)d_ws;
    int* cnt              = (int*)ws;                         // 402,000 B (+pad)
    int* wcur             = (int*)(ws + 402432);              // 32,000 B
    int* tick             = (int*)(ws + 434432);              // 8*64 B = 512 B
    unsigned short* csrW  = (unsigned short*)(ws + 434944);   // 8,000,000 B
    unsigned short* Wt    = (unsigned short*)(ws + 8434944);  // 131,072 B
    unsigned short* B2t   = (unsigned short*)(ws + 8566016);  // 8,192 B
    int* csrT             = (int*)(ws + 8574208);             // 4,864,000 B
    float* g              = (float*)(ws + 13438208);          // 8,040,000 B
    float* z              = (float*)(ws + 21478208);          // 4,020,000 B

    // zero cnt + wcur + tick (contiguous)
    hipMemsetAsync(ws, 0, 434944, stream);

    k_build<<<2048, 256, 0, stream>>>(answers, cnt, wcur, tick, csrW, csrT);
    k_prepw<<<HID + 1 + (W_NUM * 20 + 255) / 256, 256, 0, stream>>>(
        W_efc, Wt, B2t, worker_feature, W_mean, W_ls, wcur, g);
    k_gemm_mfma<<<(T_NUM + BM - 1) / BM, 256, 0, stream>>>(
        task_feature, Wt, b_efc, B2t, cnt, g);
    k_wacc<<<W_NUM, 256, 0, stream>>>(csrT, wcur, g, b_mean, b_ls, eps,
                                      out_mean, out_ls, z);
    k_gather_task<<<(T_NUM + 255) / 256, 256, 0, stream>>>(
        cnt, csrW, g, b_mean, b_ls, eps, out_mean, out_ls, z);
    k_crowd<<<(A_NUM + 255) / 256, 256, 0, stream>>>(answers, z, out_crowd);
}

// Round 11
// 233.588 us; speedup vs baseline: 1.0426x; 1.0426x over previous
//
#include <hip/hip_runtime.h>

#define T_NUM   100000
#define W_NUM   500
#define N_NODES 100500
#define A_NUM   1000000
#define FEAT    512
#define HID     128
#define CLS     10

#define CSR_STRIDE  40       // per-task worker slots; Poisson(10) tail @40 ~ 3e-16
#define CSRT_STRIDE 2432     // per-worker task slots; Binomial(1M,1/500) 9-sigma
#define BM          64       // GEMM rows per block (4 waves x 16 rows)
#define HPAD        136      // Hs row stride (bf16 elems)
#define BLD_NBLK    256      // k_build blocks
#define BLD_PER     ((A_NUM + BLD_NBLK - 1) / BLD_NBLK)   // 3907 answers/block
#define BLD_CAP     36       // per-(block,worker) LDS slots; Poisson(7.8) 10-sigma

typedef short bf16x8 __attribute__((ext_vector_type(8)));
typedef float f32x4  __attribute__((ext_vector_type(4)));

__device__ __forceinline__ unsigned short f2bf(float f) {
    unsigned int u = __float_as_uint(f);
    unsigned int r = (u + 0x7FFFu + ((u >> 16) & 1u)) >> 16;  // RNE
    return (unsigned short)r;
}

// ---------------- K1: CSR build, LDS-buffered worker lists ----------------
// Worker cursors previously serialized: 500 cursors x ~2000 same-address
// returning atomics (~150cy each) ~= 115us. Buffer (w,t) pairs in LDS per
// block (LDS-atomic chains ~8 deep), flush with ONE global atomic per
// (block,worker): cursor chain depth 2000 -> 256, csrT stores become
// contiguous ~32B runs. Task side (depth-10 chains) stays direct.
__global__ __launch_bounds__(256) void k_build(
        const int* __restrict__ answers, int* __restrict__ cnt,
        int* __restrict__ wcur,
        unsigned short* __restrict__ csrW, int* __restrict__ csrT) {
    __shared__ int lcnt[W_NUM];
    __shared__ int llist[W_NUM * BLD_CAP];

    for (int i = threadIdx.x; i < W_NUM; i += 256) lcnt[i] = 0;
    __syncthreads();

    const int base = blockIdx.x * BLD_PER;
    const int end  = (base + BLD_PER < A_NUM) ? base + BLD_PER : A_NUM;

    for (int a = base + threadIdx.x; a < end; a += 256) {
        int t = answers[a * 3 + 0];
        int w = answers[a * 3 + 1];
        int p = atomicAdd(&cnt[t], 1);
        if (p < CSR_STRIDE) csrW[(size_t)t * CSR_STRIDE + p] = (unsigned short)w;
        int s = atomicAdd(&lcnt[w], 1);
        if (s < BLD_CAP) llist[w * BLD_CAP + s] = t;
        else {                                   // ~P(Poisson(7.8)>36)=1e-18 safety
            int q = atomicAdd(&wcur[w * 16], 1);
            if (q < CSRT_STRIDE) csrT[(size_t)w * CSRT_STRIDE + q] = t;
        }
    }
    __syncthreads();

    // flush: one cursor atomic + contiguous copy per (block,worker)
    for (int w = threadIdx.x; w < W_NUM; w += 256) {
        int c = lcnt[w];
        if (c > BLD_CAP) c = BLD_CAP;
        if (c == 0) continue;
        int qb = atomicAdd(&wcur[w * 16], c);
        int* dst = csrT + (size_t)w * CSRT_STRIDE;
        for (int j = 0; j < c; j++) {
            int q = qb + j;
            if (q < CSRT_STRIDE) dst[q] = llist[w * BLD_CAP + j];
        }
    }
}

// ---------------- K2: weight preps + worker projections ----------------
__global__ void k_prepw(const float* __restrict__ W, unsigned short* __restrict__ Wt,
                        unsigned short* __restrict__ B2t,
                        const float* __restrict__ WF,
                        const float* __restrict__ Wm, const float* __restrict__ Wl,
                        const int* __restrict__ wcur,
                        float* __restrict__ g) {
    int bid = blockIdx.x;
    if (bid < HID) {
        int c = bid;
        for (int k = threadIdx.x; k < FEAT; k += blockDim.x)
            Wt[(size_t)c * FEAT + k] = f2bf(W[(size_t)k * HID + c]);
    } else if (bid == HID) {
        for (int i = threadIdx.x; i < 32 * HID; i += blockDim.x) {
            int c = i / HID, k = i % HID;
            float v = 0.f;
            if (c < 10)                 v = Wm[k * CLS + c];
            else if (c >= 16 && c < 26) v = Wl[k * CLS + (c - 16)];
            B2t[i] = f2bf(v);
        }
    } else {
        int idx = (bid - HID - 1) * blockDim.x + threadIdx.x;
        if (idx >= W_NUM * 20) return;
        int w = idx / 20, oc = idx % 20;
        const float* Wc = (oc < 10) ? (Wm + oc) : (Wl + (oc - 10));
        const float* x  = WF + (size_t)w * HID;
        float s = 0.f;
        #pragma unroll 8
        for (int k = 0; k < HID; k++) s = fmaf(x[k], Wc[k * CLS], s);
        float gi = rsqrtf((float)(wcur[w * 16] + 1)) * s;
        g[(size_t)(T_NUM + w) * 20 + oc] = gi;
    }
}

// ---------------- K3: MFMA GEMM (Hs overlaid on Bb; high occupancy) -------
__global__ __launch_bounds__(256, 7) void k_gemm_mfma(
        const float* __restrict__ A, const unsigned short* __restrict__ Wt,
        const float* __restrict__ bias, const unsigned short* __restrict__ B2t,
        const int* __restrict__ cnt, float* __restrict__ g) {
    __shared__ __align__(16) char smem[17408];

    const int tid  = threadIdx.x;
    const int lane = tid & 63;
    const int wv   = tid >> 6;                    // 0..3
    const int l15  = lane & 15;
    const int lkg  = lane >> 4;                   // 0..3
    const int row  = blockIdx.x * BM + wv * 16 + l15;
    const int rowc = row < T_NUM ? row : T_NUM - 1;   // clamp reads
    const float* aptr = A + (size_t)rowc * FEAT + lkg * 8;

    const int scol  = tid >> 1;                   // 0..127
    const int shalf = tid & 1;
    const int sswz  = (scol & 7) << 4;
    const int sb0   = (scol * 64 + shalf * 32) ^ sswz;
    const int sb1   = (scol * 64 + shalf * 32 + 16) ^ sswz;
    const unsigned short* sptr = Wt + (size_t)scol * FEAT + shalf * 16;

    const int rswz = (l15 & 7) << 4;

    f32x4 acc[8];
    #pragma unroll
    for (int nt = 0; nt < 8; nt++) acc[nt] = (f32x4){0.f, 0.f, 0.f, 0.f};

    union LU { int4 i; bf16x8 h; };
    union PK { unsigned short u[8]; bf16x8 h; };

    float4 ca0 = *(const float4*)(aptr);
    float4 ca1 = *(const float4*)(aptr + 4);
    *(int4*)(smem + sb0) = *(const int4*)(sptr);
    *(int4*)(smem + sb1) = *(const int4*)(sptr + 8);
    __syncthreads();

    for (int ks = 0; ks < 16; ks++) {
        const int k0 = ks * 32;
        float4 na0, na1;
        if (ks < 15) {
            na0 = *(const float4*)(aptr + k0 + 32);
            na1 = *(const float4*)(aptr + k0 + 36);
            char* nb = smem + (((ks + 1) & 1) << 13);
            *(int4*)(nb + sb0) = *(const int4*)(sptr + k0 + 32);
            *(int4*)(nb + sb1) = *(const int4*)(sptr + k0 + 40);
        }
        PK pk;
        pk.u[0] = f2bf(ca0.x); pk.u[1] = f2bf(ca0.y);
        pk.u[2] = f2bf(ca0.z); pk.u[3] = f2bf(ca0.w);
        pk.u[4] = f2bf(ca1.x); pk.u[5] = f2bf(ca1.y);
        pk.u[6] = f2bf(ca1.z); pk.u[7] = f2bf(ca1.w);
        const char* bb = smem + ((ks & 1) << 13);
        #pragma unroll
        for (int nt = 0; nt < 8; nt++) {
            const int boff = ((nt * 16 + l15) * 64 + lkg * 16) ^ rswz;
            LU bu; bu.i = *(const int4*)(bb + boff);
            acc[nt] = __builtin_amdgcn_mfma_f32_16x16x32_bf16(pk.h, bu.h, acc[nt], 0, 0, 0);
        }
        ca0 = na0; ca1 = na1;
        __syncthreads();
    }

    // ---- epilogue: H = relu(acc + bias) -> per-wave LDS region (bf16)
    unsigned short* hw = (unsigned short*)smem + wv * 16 * HPAD;
    #pragma unroll
    for (int nt = 0; nt < 8; nt++) {
        float bv = bias[nt * 16 + l15];
        #pragma unroll
        for (int r = 0; r < 4; r++) {
            float h = fmaxf(acc[nt][r] + bv, 0.f);
            hw[(lkg * 4 + r) * HPAD + nt * 16 + l15] = f2bf(h);
        }
    }

    // ---- second MFMA stage: g_pre = H(16x128) @ B2(128x32)
    f32x4 acc2[2];
    acc2[0] = (f32x4){0.f, 0.f, 0.f, 0.f};
    acc2[1] = (f32x4){0.f, 0.f, 0.f, 0.f};
    #pragma unroll
    for (int s = 0; s < 4; s++) {
        LU a2;
        a2.i = *(const int4*)(hw + l15 * HPAD + s * 32 + lkg * 8);
        #pragma unroll
        for (int j = 0; j < 2; j++) {
            LU b2;
            b2.i = *(const int4*)(B2t + (size_t)(j * 16 + l15) * HID + s * 32 + lkg * 8);
            acc2[j] = __builtin_amdgcn_mfma_f32_16x16x32_bf16(a2.h, b2.h, acc2[j], 0, 0, 0);
        }
    }

    // ---- scale by dinv and write g[node][0..19]
    if (l15 < 10) {
        #pragma unroll
        for (int r = 0; r < 4; r++) {
            int node = blockIdx.x * BM + wv * 16 + lkg * 4 + r;
            if (node < T_NUM) {
                float di = rsqrtf((float)(cnt[node] + 1));
                g[(size_t)node * 20 + l15]      = di * acc2[0][r];
                g[(size_t)node * 20 + 10 + l15] = di * acc2[1][r];
            }
        }
    }
}

// ---------------- K4: worker accumulation by gather + finalize ------------
__global__ __launch_bounds__(256) void k_wacc(
        const int* __restrict__ csrT, const int* __restrict__ wcur,
        const float* __restrict__ g,
        const float* __restrict__ b_mean, const float* __restrict__ b_ls,
        const float* __restrict__ eps,
        float* __restrict__ out_mean, float* __restrict__ out_ls,
        float* __restrict__ z) {
    const int w    = blockIdx.x;
    const int tid  = threadIdx.x;
    const int lane = tid & 63;
    const int wv   = tid >> 6;

    int len = wcur[w * 16];
    int lim = len < CSRT_STRIDE ? len : CSRT_STRIDE;
    const int* lst = csrT + (size_t)w * CSRT_STRIDE;

    float a[20];
    #pragma unroll
    for (int c = 0; c < 20; c++) a[c] = 0.f;

    for (int e = tid; e < lim; e += 256) {
        int t = lst[e];
        const float4* gr = (const float4*)(g + (size_t)t * 20);
        float4 v0 = gr[0], v1 = gr[1], v2 = gr[2], v3 = gr[3], v4 = gr[4];
        a[0] += v0.x; a[1] += v0.y; a[2] += v0.z; a[3] += v0.w;
        a[4] += v1.x; a[5] += v1.y; a[6] += v1.z; a[7] += v1.w;
        a[8] += v2.x; a[9] += v2.y; a[10] += v2.z; a[11] += v2.w;
        a[12] += v3.x; a[13] += v3.y; a[14] += v3.z; a[15] += v3.w;
        a[16] += v4.x; a[17] += v4.y; a[18] += v4.z; a[19] += v4.w;
    }

    #pragma unroll
    for (int off = 32; off; off >>= 1) {
        #pragma unroll
        for (int c = 0; c < 20; c++) a[c] += __shfl_down(a[c], off, 64);
    }

    __shared__ float wpart[4][20];
    __shared__ float fin[20];
    if (lane == 0) {
        #pragma unroll
        for (int c = 0; c < 20; c++) wpart[wv][c] = a[c];
    }
    __syncthreads();

    const int node = T_NUM + w;
    if (tid < 20) {
        float s = wpart[0][tid] + wpart[1][tid] + wpart[2][tid] + wpart[3][tid];
        float di = rsqrtf((float)(len + 1));
        float gv = g[(size_t)node * 20 + tid];
        if (tid < 10) {
            float m = fmaf(di, s + gv, b_mean[tid]);
            out_mean[(size_t)node * CLS + tid] = m;
            fin[tid] = m;
        } else {
            int c = tid - 10;
            float l = fmaf(di, s + gv, b_ls[c]);
            out_ls[(size_t)node * CLS + c] = l;
            fin[tid] = l;
        }
    }
    __syncthreads();
    if (tid < 10) {
        float m = fin[tid], l = fin[tid + 10];
        z[(size_t)node * CLS + tid] =
            fmaf(eps[(size_t)node * CLS + tid] * 0.01f, expf(l), m);
    }
}

// ---------------- K5: task-side gather + finalize ----------------
__global__ __launch_bounds__(256) void k_gather_task(
        const int* __restrict__ cnt, const unsigned short* __restrict__ csrW,
        const float* __restrict__ g,
        const float* __restrict__ b_mean, const float* __restrict__ b_ls,
        const float* __restrict__ eps,
        float* __restrict__ out_mean, float* __restrict__ out_ls,
        float* __restrict__ z) {
    __shared__ float gw[W_NUM * 21];
    for (int i = threadIdx.x; i < W_NUM * 20; i += blockDim.x)
        gw[(i / 20) * 21 + (i % 20)] = g[(size_t)T_NUM * 20 + i];
    __syncthreads();

    int t = blockIdx.x * blockDim.x + threadIdx.x;
    if (t >= T_NUM) return;

    int len = cnt[t];
    int lim = len < CSR_STRIDE ? len : CSR_STRIDE;
    const unsigned short* lst = csrW + (size_t)t * CSR_STRIDE;
    float am[10], al[10];
    #pragma unroll
    for (int c = 0; c < 10; c++) { am[c] = 0.f; al[c] = 0.f; }

    for (int e = 0; e < lim; e++) {
        const float* gg = &gw[lst[e] * 21];
        #pragma unroll
        for (int c = 0; c < 10; c++) {
            am[c] += gg[c];
            al[c] += gg[10 + c];
        }
    }

    float di = rsqrtf((float)(len + 1));
    union { float4 v[5]; float f[20]; } grow;
    const float4* gr = (const float4*)(g + (size_t)t * 20);
    #pragma unroll
    for (int c = 0; c < 5; c++) grow.v[c] = gr[c];

    const float2* ep2 = (const float2*)(eps + (size_t)t * CLS);
    float2* om2 = (float2*)(out_mean + (size_t)t * CLS);
    float2* ol2 = (float2*)(out_ls + (size_t)t * CLS);
    float2* z2  = (float2*)(z + (size_t)t * CLS);
    #pragma unroll
    for (int c = 0; c < 5; c++) {
        float2 ev = ep2[c];
        float m0 = fmaf(di, am[2 * c] + grow.f[2 * c], b_mean[2 * c]);
        float m1 = fmaf(di, am[2 * c + 1] + grow.f[2 * c + 1], b_mean[2 * c + 1]);
        float l0 = fmaf(di, al[2 * c] + grow.f[10 + 2 * c], b_ls[2 * c]);
        float l1 = fmaf(di, al[2 * c + 1] + grow.f[10 + 2 * c + 1], b_ls[2 * c + 1]);
        om2[c] = make_float2(m0, m1);
        ol2[c] = make_float2(l0, l1);
        z2[c]  = make_float2(fmaf(ev.x * 0.01f, expf(l0), m0),
                             fmaf(ev.y * 0.01f, expf(l1), m1));
    }
}

// ---------------- K6: crowd_out (thread per answer) ----------------
__global__ void k_crowd(const int* __restrict__ answers, const float* __restrict__ z,
                        float* __restrict__ out) {
    int a = blockIdx.x * blockDim.x + threadIdx.x;
    if (a >= A_NUM) return;
    int t = answers[a * 3 + 0];
    int w = answers[a * 3 + 1];
    const float2* zt = (const float2*)(z + (size_t)t * CLS);
    const float2* zw = (const float2*)(z + (size_t)(T_NUM + w) * CLS);
    float2* o = (float2*)(out + (size_t)a * CLS);
    #pragma unroll
    for (int c = 0; c < 5; c++) {
        float2 x = zt[c], y = zw[c];
        o[c] = make_float2(x.x * y.x, x.y * y.y);
    }
}

extern "C" void kernel_launch(void* const* d_in, const int* in_sizes, int n_in,
                              void* d_out, int out_size, void* d_ws, size_t ws_size,
                              hipStream_t stream) {
    const float* task_feature   = (const float*)d_in[0];
    const int*   answers        = (const int*)d_in[1];
    const float* worker_feature = (const float*)d_in[2];
    const float* W_efc          = (const float*)d_in[3];
    const float* b_efc          = (const float*)d_in[4];
    const float* W_mean         = (const float*)d_in[5];
    const float* b_mean         = (const float*)d_in[6];
    const float* W_ls           = (const float*)d_in[7];
    const float* b_ls           = (const float*)d_in[8];
    const float* eps            = (const float*)d_in[9];

    float* out       = (float*)d_out;
    float* out_crowd = out;                              // [A, C]
    float* out_mean  = out + (size_t)A_NUM * CLS;        // [N, C]
    float* out_ls    = out_mean + (size_t)N_NODES * CLS; // [N, C]

    // workspace layout
    char* ws = (char*)d_ws;
    int* cnt              = (int*)ws;                         // 402,000 B (+pad)
    int* wcur             = (int*)(ws + 402432);              // 32,000 B
    unsigned short* csrW  = (unsigned short*)(ws + 434944);   // 8,000,000 B
    unsigned short* Wt    = (unsigned short*)(ws + 8434944);  // 131,072 B
    unsigned short* B2t   = (unsigned short*)(ws + 8566016);  // 8,192 B
    int* csrT             = (int*)(ws + 8574208);             // 4,864,000 B
    float* g              = (float*)(ws + 13438208);          // 8,040,000 B
    float* z              = (float*)(ws + 21478208);          // 4,020,000 B

    // zero cnt + wcur (contiguous)
    hipMemsetAsync(ws, 0, 434944, stream);

    k_build<<<BLD_NBLK, 256, 0, stream>>>(answers, cnt, wcur, csrW, csrT);
    k_prepw<<<HID + 1 + (W_NUM * 20 + 255) / 256, 256, 0, stream>>>(
        W_efc, Wt, B2t, worker_feature, W_mean, W_ls, wcur, g);
    k_gemm_mfma<<<(T_NUM + BM - 1) / BM, 256, 0, stream>>>(
        task_feature, Wt, b_efc, B2t, cnt, g);
    k_wacc<<<W_NUM, 256, 0, stream>>>(csrT, wcur, g, b_mean, b_ls, eps,
                                      out_mean, out_ls, z);
    k_gather_task<<<(T_NUM + 255) / 256, 256, 0, stream>>>(
        cnt, csrW, g, b_mean, b_ls, eps, out_mean, out_ls, z);
    k_crowd<<<(A_NUM + 255) / 256, 256, 0, stream>>>(answers, z, out_crowd);
}

// Round 12
// 209.653 us; speedup vs baseline: 1.1617x; 1.1142x over previous
//
#include <hip/hip_runtime.h>

#define T_NUM   100000
#define W_NUM   500
#define N_NODES 100500
#define A_NUM   1000000
#define FEAT    512
#define HID     128
#define CLS     10

#define CSR_STRIDE  40       // per-task worker slots; Poisson(10) tail @40 ~ 3e-16
#define CSRT_STRIDE 2432     // per-worker task slots; Binomial(1M,1/500) 9-sigma
#define BM          64       // GEMM rows per block (4 waves x 16 rows)
#define HPAD        136      // Hs row stride (bf16 elems)
#define NRANGE      8        // XCDs
#define TRNG        (T_NUM / NRANGE)   // 12500 tasks per XCD
#define WRNG        64       // workers per XCD range (last range: 52)
#define CHUNK       2048
#define NCHUNK      ((A_NUM + CHUNK - 1) / CHUNK)   // 489
#define BLD_CAP     64       // per-(block,worker) LDS slots

typedef short bf16x8 __attribute__((ext_vector_type(8)));
typedef float f32x4  __attribute__((ext_vector_type(4)));

__device__ __forceinline__ unsigned short f2bf(float f) {
    unsigned int u = __float_as_uint(f);
    unsigned int r = (u + 0x7FFFu + ((u >> 16) & 1u)) >> 16;  // RNE
    return (unsigned short)r;
}

// ---------------- K1: CSR build — XCD-pinned slices + NT answer stream ----
// Mechanism (3rd hypothesis): csrW writeback thrash was never about WHERE the
// writes go (R7/R10 null) but about the 12MB answers READ stream evicting the
// dirty csrW lines from the 4MB L2. Fix: pin each block to its hardware XCD's
// task/worker slice (csrW slice ~1MB + cnt slice ~50KB fit L2) AND read
// answers with nontemporal loads (evict-first: nt lines replace each other,
// not the dirty scatter lines). Worker side: 64-worker range -> tiny LDS
// lists, single flush at end.
__global__ __launch_bounds__(256) void k_build(
        const int* __restrict__ answers, int* __restrict__ cnt,
        int* __restrict__ wcur, int* __restrict__ tick,
        unsigned short* __restrict__ csrW, int* __restrict__ csrT) {
    __shared__ int lcnt[WRNG];
    __shared__ int llist[WRNG * BLD_CAP];
    __shared__ int s_chunk;

    int xcc;
    asm volatile("s_getreg_b32 %0, hwreg(HW_REG_XCC_ID)" : "=s"(xcc));
    const int r   = xcc & (NRANGE - 1);
    const int tlo = r * TRNG, thi = tlo + TRNG;
    const int wlo = r * WRNG;

    for (int i = threadIdx.x; i < WRNG; i += 256) lcnt[i] = 0;

    for (;;) {
        __syncthreads();
        if (threadIdx.x == 0) s_chunk = atomicAdd(&tick[r * 16], 1);
        __syncthreads();
        const int c = s_chunk;
        if (c >= NCHUNK) break;
        const int base = c * CHUNK;
        const int end  = (base + CHUNK < A_NUM) ? base + CHUNK : A_NUM;
        for (int a = base + threadIdx.x; a < end; a += 256) {
            int t = __builtin_nontemporal_load(answers + a * 3);
            int w = __builtin_nontemporal_load(answers + a * 3 + 1);
            if (t >= tlo && t < thi) {
                int p = atomicAdd(&cnt[t], 1);
                if (p < CSR_STRIDE) csrW[(size_t)t * CSR_STRIDE + p] = (unsigned short)w;
            }
            int wr = w - wlo;
            if (wr >= 0 && wr < WRNG && w < W_NUM) {
                int s = atomicAdd(&lcnt[wr], 1);
                if (s < BLD_CAP) llist[wr * BLD_CAP + s] = t;
                else {                                   // overflow fallback (exactness)
                    int q = atomicAdd(&wcur[w * 16], 1);
                    if (q < CSRT_STRIDE) csrT[(size_t)w * CSRT_STRIDE + q] = t;
                }
            }
        }
    }
    __syncthreads();

    // flush: one cursor atomic + contiguous copy per (block,worker-in-range)
    for (int wr = threadIdx.x; wr < WRNG; wr += 256) {
        int w = wlo + wr;
        if (w >= W_NUM) continue;
        int c = lcnt[wr];
        if (c > BLD_CAP) c = BLD_CAP;
        if (c == 0) continue;
        int qb = atomicAdd(&wcur[w * 16], c);
        int* dst = csrT + (size_t)w * CSRT_STRIDE;
        for (int j = 0; j < c; j++) {
            int q = qb + j;
            if (q < CSRT_STRIDE) dst[q] = llist[wr * BLD_CAP + j];
        }
    }
}

// ---------------- K2: weight preps + worker projections ----------------
__global__ void k_prepw(const float* __restrict__ W, unsigned short* __restrict__ Wt,
                        unsigned short* __restrict__ B2t,
                        const float* __restrict__ WF,
                        const float* __restrict__ Wm, const float* __restrict__ Wl,
                        const int* __restrict__ wcur,
                        float* __restrict__ g) {
    int bid = blockIdx.x;
    if (bid < HID) {
        int c = bid;
        for (int k = threadIdx.x; k < FEAT; k += blockDim.x)
            Wt[(size_t)c * FEAT + k] = f2bf(W[(size_t)k * HID + c]);
    } else if (bid == HID) {
        for (int i = threadIdx.x; i < 32 * HID; i += blockDim.x) {
            int c = i / HID, k = i % HID;
            float v = 0.f;
            if (c < 10)                 v = Wm[k * CLS + c];
            else if (c >= 16 && c < 26) v = Wl[k * CLS + (c - 16)];
            B2t[i] = f2bf(v);
        }
    } else {
        int idx = (bid - HID - 1) * blockDim.x + threadIdx.x;
        if (idx >= W_NUM * 20) return;
        int w = idx / 20, oc = idx % 20;
        const float* Wc = (oc < 10) ? (Wm + oc) : (Wl + (oc - 10));
        const float* x  = WF + (size_t)w * HID;
        float s = 0.f;
        #pragma unroll 8
        for (int k = 0; k < HID; k++) s = fmaf(x[k], Wc[k * CLS], s);
        float gi = rsqrtf((float)(wcur[w * 16] + 1)) * s;
        g[(size_t)(T_NUM + w) * 20 + oc] = gi;
    }
}

// ---------------- K3: MFMA GEMM (Hs overlaid on Bb; high occupancy) -------
__global__ __launch_bounds__(256, 7) void k_gemm_mfma(
        const float* __restrict__ A, const unsigned short* __restrict__ Wt,
        const float* __restrict__ bias, const unsigned short* __restrict__ B2t,
        const int* __restrict__ cnt, float* __restrict__ g) {
    __shared__ __align__(16) char smem[17408];

    const int tid  = threadIdx.x;
    const int lane = tid & 63;
    const int wv   = tid >> 6;                    // 0..3
    const int l15  = lane & 15;
    const int lkg  = lane >> 4;                   // 0..3
    const int row  = blockIdx.x * BM + wv * 16 + l15;
    const int rowc = row < T_NUM ? row : T_NUM - 1;   // clamp reads
    const float* aptr = A + (size_t)rowc * FEAT + lkg * 8;

    const int scol  = tid >> 1;                   // 0..127
    const int shalf = tid & 1;
    const int sswz  = (scol & 7) << 4;
    const int sb0   = (scol * 64 + shalf * 32) ^ sswz;
    const int sb1   = (scol * 64 + shalf * 32 + 16) ^ sswz;
    const unsigned short* sptr = Wt + (size_t)scol * FEAT + shalf * 16;

    const int rswz = (l15 & 7) << 4;

    f32x4 acc[8];
    #pragma unroll
    for (int nt = 0; nt < 8; nt++) acc[nt] = (f32x4){0.f, 0.f, 0.f, 0.f};

    union LU { int4 i; bf16x8 h; };
    union PK { unsigned short u[8]; bf16x8 h; };

    float4 ca0 = *(const float4*)(aptr);
    float4 ca1 = *(const float4*)(aptr + 4);
    *(int4*)(smem + sb0) = *(const int4*)(sptr);
    *(int4*)(smem + sb1) = *(const int4*)(sptr + 8);
    __syncthreads();

    for (int ks = 0; ks < 16; ks++) {
        const int k0 = ks * 32;
        float4 na0, na1;
        if (ks < 15) {
            na0 = *(const float4*)(aptr + k0 + 32);
            na1 = *(const float4*)(aptr + k0 + 36);
            char* nb = smem + (((ks + 1) & 1) << 13);
            *(int4*)(nb + sb0) = *(const int4*)(sptr + k0 + 32);
            *(int4*)(nb + sb1) = *(const int4*)(sptr + k0 + 40);
        }
        PK pk;
        pk.u[0] = f2bf(ca0.x); pk.u[1] = f2bf(ca0.y);
        pk.u[2] = f2bf(ca0.z); pk.u[3] = f2bf(ca0.w);
        pk.u[4] = f2bf(ca1.x); pk.u[5] = f2bf(ca1.y);
        pk.u[6] = f2bf(ca1.z); pk.u[7] = f2bf(ca1.w);
        const char* bb = smem + ((ks & 1) << 13);
        #pragma unroll
        for (int nt = 0; nt < 8; nt++) {
            const int boff = ((nt * 16 + l15) * 64 + lkg * 16) ^ rswz;
            LU bu; bu.i = *(const int4*)(bb + boff);
            acc[nt] = __builtin_amdgcn_mfma_f32_16x16x32_bf16(pk.h, bu.h, acc[nt], 0, 0, 0);
        }
        ca0 = na0; ca1 = na1;
        __syncthreads();
    }

    // ---- epilogue: H = relu(acc + bias) -> per-wave LDS region (bf16)
    unsigned short* hw = (unsigned short*)smem + wv * 16 * HPAD;
    #pragma unroll
    for (int nt = 0; nt < 8; nt++) {
        float bv = bias[nt * 16 + l15];
        #pragma unroll
        for (int r = 0; r < 4; r++) {
            float h = fmaxf(acc[nt][r] + bv, 0.f);
            hw[(lkg * 4 + r) * HPAD + nt * 16 + l15] = f2bf(h);
        }
    }

    // ---- second MFMA stage: g_pre = H(16x128) @ B2(128x32)
    f32x4 acc2[2];
    acc2[0] = (f32x4){0.f, 0.f, 0.f, 0.f};
    acc2[1] = (f32x4){0.f, 0.f, 0.f, 0.f};
    #pragma unroll
    for (int s = 0; s < 4; s++) {
        LU a2;
        a2.i = *(const int4*)(hw + l15 * HPAD + s * 32 + lkg * 8);
        #pragma unroll
        for (int j = 0; j < 2; j++) {
            LU b2;
            b2.i = *(const int4*)(B2t + (size_t)(j * 16 + l15) * HID + s * 32 + lkg * 8);
            acc2[j] = __builtin_amdgcn_mfma_f32_16x16x32_bf16(a2.h, b2.h, acc2[j], 0, 0, 0);
        }
    }

    // ---- scale by dinv and write g[node][0..19]
    if (l15 < 10) {
        #pragma unroll
        for (int r = 0; r < 4; r++) {
            int node = blockIdx.x * BM + wv * 16 + lkg * 4 + r;
            if (node < T_NUM) {
                float di = rsqrtf((float)(cnt[node] + 1));
                g[(size_t)node * 20 + l15]      = di * acc2[0][r];
                g[(size_t)node * 20 + 10 + l15] = di * acc2[1][r];
            }
        }
    }
}

// ---------------- K4: worker accumulation by gather + finalize ------------
__global__ __launch_bounds__(256) void k_wacc(
        const int* __restrict__ csrT, const int* __restrict__ wcur,
        const float* __restrict__ g,
        const float* __restrict__ b_mean, const float* __restrict__ b_ls,
        const float* __restrict__ eps,
        float* __restrict__ out_mean, float* __restrict__ out_ls,
        float* __restrict__ z) {
    const int w    = blockIdx.x;
    const int tid  = threadIdx.x;
    const int lane = tid & 63;
    const int wv   = tid >> 6;

    int len = wcur[w * 16];
    int lim = len < CSRT_STRIDE ? len : CSRT_STRIDE;
    const int* lst = csrT + (size_t)w * CSRT_STRIDE;

    float a[20];
    #pragma unroll
    for (int c = 0; c < 20; c++) a[c] = 0.f;

    for (int e = tid; e < lim; e += 256) {
        int t = lst[e];
        const float4* gr = (const float4*)(g + (size_t)t * 20);
        float4 v0 = gr[0], v1 = gr[1], v2 = gr[2], v3 = gr[3], v4 = gr[4];
        a[0] += v0.x; a[1] += v0.y; a[2] += v0.z; a[3] += v0.w;
        a[4] += v1.x; a[5] += v1.y; a[6] += v1.z; a[7] += v1.w;
        a[8] += v2.x; a[9] += v2.y; a[10] += v2.z; a[11] += v2.w;
        a[12] += v3.x; a[13] += v3.y; a[14] += v3.z; a[15] += v3.w;
        a[16] += v4.x; a[17] += v4.y; a[18] += v4.z; a[19] += v4.w;
    }

    #pragma unroll
    for (int off = 32; off; off >>= 1) {
        #pragma unroll
        for (int c = 0; c < 20; c++) a[c] += __shfl_down(a[c], off, 64);
    }

    __shared__ float wpart[4][20];
    __shared__ float fin[20];
    if (lane == 0) {
        #pragma unroll
        for (int c = 0; c < 20; c++) wpart[wv][c] = a[c];
    }
    __syncthreads();

    const int node = T_NUM + w;
    if (tid < 20) {
        float s = wpart[0][tid] + wpart[1][tid] + wpart[2][tid] + wpart[3][tid];
        float di = rsqrtf((float)(len + 1));
        float gv = g[(size_t)node * 20 + tid];
        if (tid < 10) {
            float m = fmaf(di, s + gv, b_mean[tid]);
            out_mean[(size_t)node * CLS + tid] = m;
            fin[tid] = m;
        } else {
            int c = tid - 10;
            float l = fmaf(di, s + gv, b_ls[c]);
            out_ls[(size_t)node * CLS + c] = l;
            fin[tid] = l;
        }
    }
    __syncthreads();
    if (tid < 10) {
        float m = fin[tid], l = fin[tid + 10];
        z[(size_t)node * CLS + tid] =
            fmaf(eps[(size_t)node * CLS + tid] * 0.01f, expf(l), m);
    }
}

// ---------------- K5: task-side gather + finalize ----------------
__global__ __launch_bounds__(256) void k_gather_task(
        const int* __restrict__ cnt, const unsigned short* __restrict__ csrW,
        const float* __restrict__ g,
        const float* __restrict__ b_mean, const float* __restrict__ b_ls,
        const float* __restrict__ eps,
        float* __restrict__ out_mean, float* __restrict__ out_ls,
        float* __restrict__ z) {
    __shared__ float gw[W_NUM * 21];
    for (int i = threadIdx.x; i < W_NUM * 20; i += blockDim.x)
        gw[(i / 20) * 21 + (i % 20)] = g[(size_t)T_NUM * 20 + i];
    __syncthreads();

    int t = blockIdx.x * blockDim.x + threadIdx.x;
    if (t >= T_NUM) return;

    int len = cnt[t];
    int lim = len < CSR_STRIDE ? len : CSR_STRIDE;
    const unsigned short* lst = csrW + (size_t)t * CSR_STRIDE;
    float am[10], al[10];
    #pragma unroll
    for (int c = 0; c < 10; c++) { am[c] = 0.f; al[c] = 0.f; }

    for (int e = 0; e < lim; e++) {
        const float* gg = &gw[lst[e] * 21];
        #pragma unroll
        for (int c = 0; c < 10; c++) {
            am[c] += gg[c];
            al[c] += gg[10 + c];
        }
    }

    float di = rsqrtf((float)(len + 1));
    union { float4 v[5]; float f[20]; } grow;
    const float4* gr = (const float4*)(g + (size_t)t * 20);
    #pragma unroll
    for (int c = 0; c < 5; c++) grow.v[c] = gr[c];

    const float2* ep2 = (const float2*)(eps + (size_t)t * CLS);
    float2* om2 = (float2*)(out_mean + (size_t)t * CLS);
    float2* ol2 = (float2*)(out_ls + (size_t)t * CLS);
    float2* z2  = (float2*)(z + (size_t)t * CLS);
    #pragma unroll
    for (int c = 0; c < 5; c++) {
        float2 ev = ep2[c];
        float m0 = fmaf(di, am[2 * c] + grow.f[2 * c], b_mean[2 * c]);
        float m1 = fmaf(di, am[2 * c + 1] + grow.f[2 * c + 1], b_mean[2 * c + 1]);
        float l0 = fmaf(di, al[2 * c] + grow.f[10 + 2 * c], b_ls[2 * c]);
        float l1 = fmaf(di, al[2 * c + 1] + grow.f[10 + 2 * c + 1], b_ls[2 * c + 1]);
        om2[c] = make_float2(m0, m1);
        ol2[c] = make_float2(l0, l1);
        z2[c]  = make_float2(fmaf(ev.x * 0.01f, expf(l0), m0),
                             fmaf(ev.y * 0.01f, expf(l1), m1));
    }
}

// ---------------- K6: crowd_out (thread per answer) ----------------
__global__ void k_crowd(const int* __restrict__ answers, const float* __restrict__ z,
                        float* __restrict__ out) {
    int a = blockIdx.x * blockDim.x + threadIdx.x;
    if (a >= A_NUM) return;
    int t = answers[a * 3 + 0];
    int w = answers[a * 3 + 1];
    const float2* zt = (const float2*)(z + (size_t)t * CLS);
    const float2* zw = (const float2*)(z + (size_t)(T_NUM + w) * CLS);
    float2* o = (float2*)(out + (size_t)a * CLS);
    #pragma unroll
    for (int c = 0; c < 5; c++) {
        float2 x = zt[c], y = zw[c];
        o[c] = make_float2(x.x * y.x, x.y * y.y);
    }
}

extern "C" void kernel_launch(void* const* d_in, const int* in_sizes, int n_in,
                              void* d_out, int out_size, void* d_ws, size_t ws_size,
                              hipStream_t stream) {
    const float* task_feature   = (const float*)d_in[0];
    const int*   answers        = (const int*)d_in[1];
    const float* worker_feature = (const float*)d_in[2];
    const float* W_efc          = (const float*)d_in[3];
    const float* b_efc          = (const float*)d_in[4];
    const float* W_mean         = (const float*)d_in[5];
    const float* b_mean         = (const float*)d_in[6];
    const float* W_ls           = (const float*)d_in[7];
    const float* b_ls           = (const float*)d_in[8];
    const float* eps            = (const float*)d_in[9];

    float* out       = (float*)d_out;
    float* out_crowd = out;                              // [A, C]
    float* out_mean  = out + (size_t)A_NUM * CLS;        // [N, C]
    float* out_ls    = out_mean + (size_t)N_NODES * CLS; // [N, C]

    // workspace layout
    char* ws = (char*)d_ws;
    int* cnt              = (int*)ws;                         // 402,000 B (+pad)
    int* wcur             = (int*)(ws + 402432);              // 32,000 B
    int* tick             = (int*)(ws + 434432);              // 512 B
    unsigned short* csrW  = (unsigned short*)(ws + 434944);   // 8,000,000 B
    unsigned short* Wt    = (unsigned short*)(ws + 8434944);  // 131,072 B
    unsigned short* B2t   = (unsigned short*)(ws + 8566016);  // 8,192 B
    int* csrT             = (int*)(ws + 8574208);             // 4,864,000 B
    float* g              = (float*)(ws + 13438208);          // 8,040,000 B
    float* z              = (float*)(ws + 21478208);          // 4,020,000 B

    // zero cnt + wcur + tick (contiguous)
    hipMemsetAsync(ws, 0, 434944, stream);

    k_build<<<2048, 256, 0, stream>>>(answers, cnt, wcur, tick, csrW, csrT);
    k_prepw<<<HID + 1 + (W_NUM * 20 + 255) / 256, 256, 0, stream>>>(
        W_efc, Wt, B2t, worker_feature, W_mean, W_ls, wcur, g);
    k_gemm_mfma<<<(T_NUM + BM - 1) / BM, 256, 0, stream>>>(
        task_feature, Wt, b_efc, B2t, cnt, g);
    k_wacc<<<W_NUM, 256, 0, stream>>>(csrT, wcur, g, b_mean, b_ls, eps,
                                      out_mean, out_ls, z);
    k_gather_task<<<(T_NUM + 255) / 256, 256, 0, stream>>>(
        cnt, csrW, g, b_mean, b_ls, eps, out_mean, out_ls, z);
    k_crowd<<<(A_NUM + 255) / 256, 256, 0, stream>>>(answers, z, out_crowd);
}

// Round 13
// 208.061 us; speedup vs baseline: 1.1706x; 1.0077x over previous
//
#include <hip/hip_runtime.h>

#define T_NUM   100000
#define W_NUM   500
#define N_NODES 100500
#define A_NUM   1000000
#define FEAT    512
#define HID     128
#define CLS     10

#define CSR_STRIDE  40       // per-task worker slots; Poisson(10) tail @40 ~ 3e-16
#define CSRT_STRIDE 2432     // per-worker task slots; Binomial(1M,1/500) 9-sigma
#define BM          64       // GEMM rows per block (4 waves x 16 rows)
#define HPAD        136      // Hs row stride (bf16 elems)
#define NRANGE      8        // XCDs
#define TRNG        (T_NUM / NRANGE)   // 12500 tasks per XCD
#define WRNG        64       // workers per XCD range (last range: 52)
#define CHUNK       2048
#define NCHUNK      ((A_NUM + CHUNK - 1) / CHUNK)   // 489
#define BLD_CAP     64       // per-(block,worker) LDS slots

typedef short bf16x8 __attribute__((ext_vector_type(8)));
typedef float f32x4  __attribute__((ext_vector_type(4)));

// one-instruction packed f32->bf16 (RNE) — gfx950 v_cvt_pk_bf16_f32 (no builtin)
__device__ __forceinline__ unsigned cvtpk(float lo, float hi) {
    unsigned r;
    asm("v_cvt_pk_bf16_f32 %0, %1, %2" : "=v"(r) : "v"(lo), "v"(hi));
    return r;
}
__device__ __forceinline__ unsigned short f2bf1(float x) {
    return (unsigned short)cvtpk(x, x);
}

// ---------------- K1: CSR build — XCD-pinned slices + NT answer stream ----
__global__ __launch_bounds__(256) void k_build(
        const int* __restrict__ answers, int* __restrict__ cnt,
        int* __restrict__ wcur, int* __restrict__ tick,
        unsigned short* __restrict__ csrW, int* __restrict__ csrT) {
    __shared__ int lcnt[WRNG];
    __shared__ int llist[WRNG * BLD_CAP];
    __shared__ int s_chunk;

    int xcc;
    asm volatile("s_getreg_b32 %0, hwreg(HW_REG_XCC_ID)" : "=s"(xcc));
    const int r   = xcc & (NRANGE - 1);
    const int tlo = r * TRNG, thi = tlo + TRNG;
    const int wlo = r * WRNG;

    for (int i = threadIdx.x; i < WRNG; i += 256) lcnt[i] = 0;

    for (;;) {
        __syncthreads();
        if (threadIdx.x == 0) s_chunk = atomicAdd(&tick[r * 16], 1);
        __syncthreads();
        const int c = s_chunk;
        if (c >= NCHUNK) break;
        const int base = c * CHUNK;
        const int end  = (base + CHUNK < A_NUM) ? base + CHUNK : A_NUM;
        for (int a = base + threadIdx.x; a < end; a += 256) {
            int t = __builtin_nontemporal_load(answers + a * 3);
            int w = __builtin_nontemporal_load(answers + a * 3 + 1);
            if (t >= tlo && t < thi) {
                int p = atomicAdd(&cnt[t], 1);
                if (p < CSR_STRIDE) csrW[(size_t)t * CSR_STRIDE + p] = (unsigned short)w;
            }
            int wr = w - wlo;
            if (wr >= 0 && wr < WRNG && w < W_NUM) {
                int s = atomicAdd(&lcnt[wr], 1);
                if (s < BLD_CAP) llist[wr * BLD_CAP + s] = t;
                else {                                   // overflow fallback (exactness)
                    int q = atomicAdd(&wcur[w * 16], 1);
                    if (q < CSRT_STRIDE) csrT[(size_t)w * CSRT_STRIDE + q] = t;
                }
            }
        }
    }
    __syncthreads();

    for (int wr = threadIdx.x; wr < WRNG; wr += 256) {
        int w = wlo + wr;
        if (w >= W_NUM) continue;
        int c = lcnt[wr];
        if (c > BLD_CAP) c = BLD_CAP;
        if (c == 0) continue;
        int qb = atomicAdd(&wcur[w * 16], c);
        int* dst = csrT + (size_t)w * CSRT_STRIDE;
        for (int j = 0; j < c; j++) {
            int q = qb + j;
            if (q < CSRT_STRIDE) dst[q] = llist[wr * BLD_CAP + j];
        }
    }
}

// ---------------- K2: weight preps + worker projections ----------------
__global__ void k_prepw(const float* __restrict__ W, unsigned short* __restrict__ Wt,
                        unsigned short* __restrict__ B2t,
                        const float* __restrict__ WF,
                        const float* __restrict__ Wm, const float* __restrict__ Wl,
                        const int* __restrict__ wcur,
                        float* __restrict__ g) {
    int bid = blockIdx.x;
    if (bid < HID) {
        int c = bid;
        for (int k = threadIdx.x; k < FEAT; k += blockDim.x)
            Wt[(size_t)c * FEAT + k] = f2bf1(W[(size_t)k * HID + c]);
    } else if (bid == HID) {
        for (int i = threadIdx.x; i < 32 * HID; i += blockDim.x) {
            int c = i / HID, k = i % HID;
            float v = 0.f;
            if (c < 10)                 v = Wm[k * CLS + c];
            else if (c >= 16 && c < 26) v = Wl[k * CLS + (c - 16)];
            B2t[i] = f2bf1(v);
        }
    } else {
        int idx = (bid - HID - 1) * blockDim.x + threadIdx.x;
        if (idx >= W_NUM * 20) return;
        int w = idx / 20, oc = idx % 20;
        const float* Wc = (oc < 10) ? (Wm + oc) : (Wl + (oc - 10));
        const float* x  = WF + (size_t)w * HID;
        float s = 0.f;
        #pragma unroll 8
        for (int k = 0; k < HID; k++) s = fmaf(x[k], Wc[k * CLS], s);
        float gi = rsqrtf((float)(wcur[w * 16] + 1)) * s;
        g[(size_t)(T_NUM + w) * 20 + oc] = gi;
    }
}

// ---------------- K3: MFMA GEMM (cvt_pk A-conversion; high occupancy) -----
__global__ __launch_bounds__(256, 7) void k_gemm_mfma(
        const float* __restrict__ A, const unsigned short* __restrict__ Wt,
        const float* __restrict__ bias, const unsigned short* __restrict__ B2t,
        const int* __restrict__ cnt, float* __restrict__ g) {
    __shared__ __align__(16) char smem[17408];

    const int tid  = threadIdx.x;
    const int lane = tid & 63;
    const int wv   = tid >> 6;                    // 0..3
    const int l15  = lane & 15;
    const int lkg  = lane >> 4;                   // 0..3
    const int row  = blockIdx.x * BM + wv * 16 + l15;
    const int rowc = row < T_NUM ? row : T_NUM - 1;   // clamp reads
    const float* aptr = A + (size_t)rowc * FEAT + lkg * 8;

    const int scol  = tid >> 1;                   // 0..127
    const int shalf = tid & 1;
    const int sswz  = (scol & 7) << 4;
    const int sb0   = (scol * 64 + shalf * 32) ^ sswz;
    const int sb1   = (scol * 64 + shalf * 32 + 16) ^ sswz;
    const unsigned short* sptr = Wt + (size_t)scol * FEAT + shalf * 16;

    const int rswz = (l15 & 7) << 4;

    f32x4 acc[8];
    #pragma unroll
    for (int nt = 0; nt < 8; nt++) acc[nt] = (f32x4){0.f, 0.f, 0.f, 0.f};

    union LU { int4 i; bf16x8 h; };
    union PK { unsigned u[4]; bf16x8 h; };

    float4 ca0 = *(const float4*)(aptr);
    float4 ca1 = *(const float4*)(aptr + 4);
    *(int4*)(smem + sb0) = *(const int4*)(sptr);
    *(int4*)(smem + sb1) = *(const int4*)(sptr + 8);
    __syncthreads();

    for (int ks = 0; ks < 16; ks++) {
        const int k0 = ks * 32;
        float4 na0, na1;
        if (ks < 15) {
            na0 = *(const float4*)(aptr + k0 + 32);
            na1 = *(const float4*)(aptr + k0 + 36);
            char* nb = smem + (((ks + 1) & 1) << 13);
            *(int4*)(nb + sb0) = *(const int4*)(sptr + k0 + 32);
            *(int4*)(nb + sb1) = *(const int4*)(sptr + k0 + 40);
        }
        PK pk;
        pk.u[0] = cvtpk(ca0.x, ca0.y);
        pk.u[1] = cvtpk(ca0.z, ca0.w);
        pk.u[2] = cvtpk(ca1.x, ca1.y);
        pk.u[3] = cvtpk(ca1.z, ca1.w);
        const char* bb = smem + ((ks & 1) << 13);
        #pragma unroll
        for (int nt = 0; nt < 8; nt++) {
            const int boff = ((nt * 16 + l15) * 64 + lkg * 16) ^ rswz;
            LU bu; bu.i = *(const int4*)(bb + boff);
            acc[nt] = __builtin_amdgcn_mfma_f32_16x16x32_bf16(pk.h, bu.h, acc[nt], 0, 0, 0);
        }
        ca0 = na0; ca1 = na1;
        __syncthreads();
    }

    // ---- epilogue: H = relu(acc + bias) -> per-wave LDS region (bf16)
    unsigned short* hw = (unsigned short*)smem + wv * 16 * HPAD;
    #pragma unroll
    for (int nt = 0; nt < 8; nt++) {
        float bv = bias[nt * 16 + l15];
        #pragma unroll
        for (int r = 0; r < 4; r++) {
            float h = fmaxf(acc[nt][r] + bv, 0.f);
            hw[(lkg * 4 + r) * HPAD + nt * 16 + l15] = f2bf1(h);
        }
    }

    // ---- second MFMA stage: g_pre = H(16x128) @ B2(128x32)
    f32x4 acc2[2];
    acc2[0] = (f32x4){0.f, 0.f, 0.f, 0.f};
    acc2[1] = (f32x4){0.f, 0.f, 0.f, 0.f};
    #pragma unroll
    for (int s = 0; s < 4; s++) {
        LU a2;
        a2.i = *(const int4*)(hw + l15 * HPAD + s * 32 + lkg * 8);
        #pragma unroll
        for (int j = 0; j < 2; j++) {
            LU b2;
            b2.i = *(const int4*)(B2t + (size_t)(j * 16 + l15) * HID + s * 32 + lkg * 8);
            acc2[j] = __builtin_amdgcn_mfma_f32_16x16x32_bf16(a2.h, b2.h, acc2[j], 0, 0, 0);
        }
    }

    // ---- scale by dinv and write g[node][0..19]
    if (l15 < 10) {
        #pragma unroll
        for (int r = 0; r < 4; r++) {
            int node = blockIdx.x * BM + wv * 16 + lkg * 4 + r;
            if (node < T_NUM) {
                float di = rsqrtf((float)(cnt[node] + 1));
                g[(size_t)node * 20 + l15]      = di * acc2[0][r];
                g[(size_t)node * 20 + 10 + l15] = di * acc2[1][r];
            }
        }
    }
}

// ---------------- K4: worker accumulation by gather + finalize ------------
__global__ __launch_bounds__(256) void k_wacc(
        const int* __restrict__ csrT, const int* __restrict__ wcur,
        const float* __restrict__ g,
        const float* __restrict__ b_mean, const float* __restrict__ b_ls,
        const float* __restrict__ eps,
        float* __restrict__ out_mean, float* __restrict__ out_ls,
        float* __restrict__ z) {
    const int w    = blockIdx.x;
    const int tid  = threadIdx.x;
    const int lane = tid & 63;
    const int wv   = tid >> 6;

    int len = wcur[w * 16];
    int lim = len < CSRT_STRIDE ? len : CSRT_STRIDE;
    const int* lst = csrT + (size_t)w * CSRT_STRIDE;

    float a[20];
    #pragma unroll
    for (int c = 0; c < 20; c++) a[c] = 0.f;

    for (int e = tid; e < lim; e += 256) {
        int t = lst[e];
        const float4* gr = (const float4*)(g + (size_t)t * 20);
        float4 v0 = gr[0], v1 = gr[1], v2 = gr[2], v3 = gr[3], v4 = gr[4];
        a[0] += v0.x; a[1] += v0.y; a[2] += v0.z; a[3] += v0.w;
        a[4] += v1.x; a[5] += v1.y; a[6] += v1.z; a[7] += v1.w;
        a[8] += v2.x; a[9] += v2.y; a[10] += v2.z; a[11] += v2.w;
        a[12] += v3.x; a[13] += v3.y; a[14] += v3.z; a[15] += v3.w;
        a[16] += v4.x; a[17] += v4.y; a[18] += v4.z; a[19] += v4.w;
    }

    #pragma unroll
    for (int off = 32; off; off >>= 1) {
        #pragma unroll
        for (int c = 0; c < 20; c++) a[c] += __shfl_down(a[c], off, 64);
    }

    __shared__ float wpart[4][20];
    __shared__ float fin[20];
    if (lane == 0) {
        #pragma unroll
        for (int c = 0; c < 20; c++) wpart[wv][c] = a[c];
    }
    __syncthreads();

    const int node = T_NUM + w;
    if (tid < 20) {
        float s = wpart[0][tid] + wpart[1][tid] + wpart[2][tid] + wpart[3][tid];
        float di = rsqrtf((float)(len + 1));
        float gv = g[(size_t)node * 20 + tid];
        if (tid < 10) {
            float m = fmaf(di, s + gv, b_mean[tid]);
            out_mean[(size_t)node * CLS + tid] = m;
            fin[tid] = m;
        } else {
            int c = tid - 10;
            float l = fmaf(di, s + gv, b_ls[c]);
            out_ls[(size_t)node * CLS + c] = l;
            fin[tid] = l;
        }
    }
    __syncthreads();
    if (tid < 10) {
        float m = fin[tid], l = fin[tid + 10];
        z[(size_t)node * CLS + tid] =
            fmaf(eps[(size_t)node * CLS + tid] * 0.01f, expf(l), m);
    }
}

// ---------------- K5: task-side gather + finalize ----------------
__global__ __launch_bounds__(256) void k_gather_task(
        const int* __restrict__ cnt, const unsigned short* __restrict__ csrW,
        const float* __restrict__ g,
        const float* __restrict__ b_mean, const float* __restrict__ b_ls,
        const float* __restrict__ eps,
        float* __restrict__ out_mean, float* __restrict__ out_ls,
        float* __restrict__ z) {
    __shared__ float gw[W_NUM * 21];
    for (int i = threadIdx.x; i < W_NUM * 20; i += blockDim.x)
        gw[(i / 20) * 21 + (i % 20)] = g[(size_t)T_NUM * 20 + i];
    __syncthreads();

    int t = blockIdx.x * blockDim.x + threadIdx.x;
    if (t >= T_NUM) return;

    int len = cnt[t];
    int lim = len < CSR_STRIDE ? len : CSR_STRIDE;
    const unsigned short* lst = csrW + (size_t)t * CSR_STRIDE;
    float am[10], al[10];
    #pragma unroll
    for (int c = 0; c < 10; c++) { am[c] = 0.f; al[c] = 0.f; }

    for (int e = 0; e < lim; e++) {
        const float* gg = &gw[lst[e] * 21];
        #pragma unroll
        for (int c = 0; c < 10; c++) {
            am[c] += gg[c];
            al[c] += gg[10 + c];
        }
    }

    float di = rsqrtf((float)(len + 1));
    union { float4 v[5]; float f[20]; } grow;
    const float4* gr = (const float4*)(g + (size_t)t * 20);
    #pragma unroll
    for (int c = 0; c < 5; c++) grow.v[c] = gr[c];

    const float2* ep2 = (const float2*)(eps + (size_t)t * CLS);
    float2* om2 = (float2*)(out_mean + (size_t)t * CLS);
    float2* ol2 = (float2*)(out_ls + (size_t)t * CLS);
    float2* z2  = (float2*)(z + (size_t)t * CLS);
    #pragma unroll
    for (int c = 0; c < 5; c++) {
        float2 ev = ep2[c];
        float m0 = fmaf(di, am[2 * c] + grow.f[2 * c], b_mean[2 * c]);
        float m1 = fmaf(di, am[2 * c + 1] + grow.f[2 * c + 1], b_mean[2 * c + 1]);
        float l0 = fmaf(di, al[2 * c] + grow.f[10 + 2 * c], b_ls[2 * c]);
        float l1 = fmaf(di, al[2 * c + 1] + grow.f[10 + 2 * c + 1], b_ls[2 * c + 1]);
        om2[c] = make_float2(m0, m1);
        ol2[c] = make_float2(l0, l1);
        z2[c]  = make_float2(fmaf(ev.x * 0.01f, expf(l0), m0),
                             fmaf(ev.y * 0.01f, expf(l1), m1));
    }
}

// ---------------- K6: crowd_out — 5 threads/answer, coalesced stores ------
// thread i -> (answer a = i/5, pair c2 = i%5); writes out[2i] -> consecutive
// lanes write consecutive float2 (perfect coalescing). z rows shared 5-way.
__global__ void k_crowd(const int* __restrict__ answers, const float* __restrict__ z,
                        float* __restrict__ out) {
    int i = blockIdx.x * blockDim.x + threadIdx.x;
    if (i >= A_NUM * 5) return;
    int a = i / 5, c2 = i % 5;
    int t = answers[a * 3 + 0];
    int w = answers[a * 3 + 1];
    float2 x = *(const float2*)(z + (size_t)t * CLS + c2 * 2);
    float2 y = *(const float2*)(z + (size_t)(T_NUM + w) * CLS + c2 * 2);
    *(float2*)(out + (size_t)i * 2) = make_float2(x.x * y.x, x.y * y.y);
}

extern "C" void kernel_launch(void* const* d_in, const int* in_sizes, int n_in,
                              void* d_out, int out_size, void* d_ws, size_t ws_size,
                              hipStream_t stream) {
    const float* task_feature   = (const float*)d_in[0];
    const int*   answers        = (const int*)d_in[1];
    const float* worker_feature = (const float*)d_in[2];
    const float* W_efc          = (const float*)d_in[3];
    const float* b_efc          = (const float*)d_in[4];
    const float* W_mean         = (const float*)d_in[5];
    const float* b_mean         = (const float*)d_in[6];
    const float* W_ls           = (const float*)d_in[7];
    const float* b_ls           = (const float*)d_in[8];
    const float* eps            = (const float*)d_in[9];

    float* out       = (float*)d_out;
    float* out_crowd = out;                              // [A, C]
    float* out_mean  = out + (size_t)A_NUM * CLS;        // [N, C]
    float* out_ls    = out_mean + (size_t)N_NODES * CLS; // [N, C]

    // workspace layout
    char* ws = (char*)d_ws;
    int* cnt              = (int*)ws;                         // 402,000 B (+pad)
    int* wcur             = (int*)(ws + 402432);              // 32,000 B
    int* tick             = (int*)(ws + 434432);              // 512 B
    unsigned short* csrW  = (unsigned short*)(ws + 434944);   // 8,000,000 B
    unsigned short* Wt    = (unsigned short*)(ws + 8434944);  // 131,072 B
    unsigned short* B2t   = (unsigned short*)(ws + 8566016);  // 8,192 B
    int* csrT             = (int*)(ws + 8574208);             // 4,864,000 B
    float* g              = (float*)(ws + 13438208);          // 8,040,000 B
    float* z              = (float*)(ws + 21478208);          // 4,020,000 B

    // zero cnt + wcur + tick (contiguous)
    hipMemsetAsync(ws, 0, 434944, stream);

    k_build<<<2048, 256, 0, stream>>>(answers, cnt, wcur, tick, csrW, csrT);
    k_prepw<<<HID + 1 + (W_NUM * 20 + 255) / 256, 256, 0, stream>>>(
        W_efc, Wt, B2t, worker_feature, W_mean, W_ls, wcur, g);
    k_gemm_mfma<<<(T_NUM + BM - 1) / BM, 256, 0, stream>>>(
        task_feature, Wt, b_efc, B2t, cnt, g);
    k_wacc<<<W_NUM, 256, 0, stream>>>(csrT, wcur, g, b_mean, b_ls, eps,
                                      out_mean, out_ls, z);
    k_gather_task<<<(T_NUM + 255) / 256, 256, 0, stream>>>(
        cnt, csrW, g, b_mean, b_ls, eps, out_mean, out_ls, z);
    k_crowd<<<(A_NUM * 5 + 255) / 256, 256, 0, stream>>>(answers, z, out_crowd);
}